// Round 11
// baseline (446.498 us; speedup 1.0000x reference)
//
#include <hip/hip_runtime.h>
#include <stdint.h>

// ---------------------------------------------------------------------------
// scores[b,s] = v . tanh( hidden[b] @ Wh + bias + enc[s,b] @ We )
// out[b,s]   = softmax_s(scores)
// Big GEMM: enc_flat[M=65536,K=1024] @ We[K=1024,N=512], bf16 MFMA.
// R12: isolate the last untested factor. Audit showed every A-stage so far
//     had wave-lanes spanning rows: R11's staging instr touched 64 distinct
//     128B lines (4KB stride) -> per-CU miss-tracking caps concurrency,
//     which is why deeper prefetch (R9) never helped. The one clean-staging
//     variant (R10, 8 lines/instr) was confounded by 16-MFMA phases.
//     Now: R11 mega-phases (128 MFMA/barrier) + contiguous staging:
//     flat f=j*256+tid -> row f>>5, chunk f&31; each instr = 2 rows x 512B
//     contiguous = 8 lines. Thread scatters its 8 row-chunks to LDS as
//     8 x ds_write_b64; step-stride padded 2048->2080 -> write banks 2-way
//     (free); read pattern unchanged (verified conflict-free, 0 in PMC).
// ---------------------------------------------------------------------------

typedef float  floatx4 __attribute__((ext_vector_type(4)));
typedef __bf16 bf16x4  __attribute__((ext_vector_type(4)));
typedef __bf16 bf16x8  __attribute__((ext_vector_type(8)));
typedef short  short8  __attribute__((ext_vector_type(8)));

union bfu  { bf16x8 v; short8 s; };
union bfu4 { bf16x4 v; uint2 u; };

#define LOG2E_X2 2.8853900817779268f
#define SB() __builtin_amdgcn_sched_barrier(0)

// raw barrier: wait own LDS ops only; global prefetches ride across.
#define BARX()                                             \
  do {                                                     \
    asm volatile("s_waitcnt lgkmcnt(0)" ::: "memory");     \
    SB();                                                  \
    __builtin_amdgcn_s_barrier();                          \
    SB();                                                  \
  } while (0)

// ---- kernel 0: W[512:1536,:] -> fragment-packed bf16 B.
// Bp frag(T,wc,ct) base elem = ((T*4+wc)*8+ct)*512; lane (q*16+t) holds 8 k.
__global__ void wt_convert(const float* __restrict__ W, __bf16* __restrict__ Bp) {
  __shared__ float tile[64][65];                 // +1 pad: conflict-free both ways
  const int kt = blockIdx.x >> 3;                // 16 k-tiles (64 k each)
  const int nt = blockIdx.x & 7;                 // 8 n-tiles (64 n each)
  const int c  = threadIdx.x & 63;
  const int r4 = threadIdx.x >> 6;               // 4 rows per pass
  #pragma unroll 4
  for (int i = 0; i < 16; i++) {
    int r = i * 4 + r4;                          // k-local
    tile[r][c] = W[(long)(512 + kt * 64 + r) * 512 + nt * 64 + c];
  }
  __syncthreads();
  const int n_loc = threadIdx.x & 63;
  const int kc4   = threadIdx.x >> 6;            // 0..3
  const int n_g   = nt * 64 + n_loc;
  const int wc    = n_g >> 7;
  const int ct    = (n_g >> 4) & 7;
  const int t     = n_g & 15;
  #pragma unroll
  for (int i = 0; i < 2; i++) {
    int chunk = i * 4 + kc4;                     // k_loc = chunk*8 + j
    int k_g   = kt * 64 + chunk * 8;
    int T     = k_g >> 5;
    int q     = (k_g >> 3) & 3;
    union bfu u;
    #pragma unroll
    for (int j = 0; j < 8; j++) u.v[j] = (__bf16)tile[chunk * 8 + j][n_loc];
    long cidx = ((long)(T * 4 + wc) * 8 + ct) * 64 + q * 16 + t;
    *(bf16x8*)(Bp + cidx * 8) = u.v;
  }
}

// ---- kernel 1: hproj[b][n] = bias[n] + sum_k hidden[b,k] * W[k,n]  (k<512)
__global__ void hproj_kernel(const float* __restrict__ hidden,
                             const float* __restrict__ W,
                             const float* __restrict__ bias,
                             float* __restrict__ hproj) {
  const int tid = threadIdx.x;            // n
  const int b_  = blockIdx.x >> 2;
  const int kc  = blockIdx.x & 3;
  __shared__ float hid[128];
  if (tid < 128) hid[tid] = hidden[b_ * 512 + kc * 128 + tid];
  __syncthreads();
  float acc = (kc == 0) ? bias[tid] : 0.f;
  const float* Wp = W + (long)(kc * 128) * 512 + tid;
  #pragma unroll 8
  for (int k = 0; k < 128; k++) acc = fmaf(hid[k], Wp[(long)k * 512], acc);
  atomicAdd(&hproj[b_ * 512 + tid], acc);
}

// ---- kernel 2: GEMM + tanh/v-dot epilogue; BK=128 mega-phases,
//                contiguous-line A staging.
// LDS buffer (bf16): element (m, step s, k-in-step kk=c*8+jj):
//   addr = s*2080 + c*512 + ((m*8) ^ (c*16)) + jj        (2080 = 2048+32 pad)
// Staging (thread tid, chunk j2 = 0..7):
//   row m = j2*8 + (tid>>5); 4 floats at k-phase (tid&31)*4.
//   Global: instr j2 = 2 rows x 512B contiguous = 8 lines.   [the fix]
//   LDS: s=(tid&31)>>3, c=((tid&31)>>1)&3, j0=(tid&1)*4 ->
//     awbase = s*2080 + c*512 + (((tid>>5)*8) ^ (c*16)) + j0; + j2*64.
//   Banks: 16 distinct/half-wave -> 2-way b64 = free.
__global__ __launch_bounds__(256, 2) void gemm_score(
    const float* __restrict__ enc,    // [65536][1024] fp32
    const __bf16* __restrict__ Bp,    // packed B, 1 MB
    const float* __restrict__ hproj,  // [64][512]
    const float* __restrict__ v,      // [512]
    float* __restrict__ scores)       // [64][1024]  ([b][s])
{
  __shared__ __bf16 ldsA[2][8320];   // 2 x 16.25 KB
  __shared__ float bscore[64];

  const int tid  = threadIdx.x;
  const int lane = tid & 63;
  const int wc   = tid >> 6;      // wave -> n-range [wc*128, +128)
  const int q    = lane >> 4;
  const int t    = lane & 15;
  const long m0  = (long)blockIdx.x * 64;

  // staging: base row = tid>>5 (chunk j2 adds j2*8 rows); col = (tid&31)*4
  const float* ap = enc + (m0 + (tid >> 5)) * 1024 + (tid & 31) * 4;
  const int skk = tid & 31;
  const int ss  = skk >> 3;
  const int cc  = (skk >> 1) & 3;
  const int j0  = (skk & 1) * 4;
  const int awoff = ss * 2080 + cc * 512 + (((tid >> 5) * 8) ^ (cc * 16)) + j0;

  // fragment read bases (step/rt offsets are compile-time immediates)
  const __bf16* ar0 = &ldsA[0][q * 512 + ((t * 8) ^ (q * 16))];
  const __bf16* ar1 = &ldsA[1][q * 512 + ((t * 8) ^ (q * 16))];

  // packed-B per-lane base
  const __bf16* bpb = Bp + (long)wc * 4096 + (long)lane * 8;

  if (tid < 64) bscore[tid] = 0.f;

  floatx4 acc[4][8];
  #pragma unroll
  for (int i = 0; i < 4; i++)
    #pragma unroll
    for (int j = 0; j < 8; j++)
      acc[i][j] = (floatx4){0.f, 0.f, 0.f, 0.f};

  floatx4 ra[8];       // A staging: 8 x 16B chunks (8 rows), 32 VGPR
  short8  bfr[2][8];   // B fragments, rolling double buffer (64 VGPR)

  auto issueA = [&](int P) {                 // 8 contiguous-line 16B loads
    const float* p = ap + P * 128;
    #pragma unroll
    for (int j2 = 0; j2 < 8; j2++)
      ra[j2] = *(const floatx4*)(p + (long)j2 * 8 * 1024);
  };
  auto writeA = [&](int b) {                 // cvt once + 8 x ds_write_b64
    __bf16* dst = &ldsA[b][awoff];
    #pragma unroll
    for (int j2 = 0; j2 < 8; j2++) {
      union bfu4 u;
      #pragma unroll
      for (int j = 0; j < 4; j++) u.v[j] = (__bf16)ra[j2][j];
      *(bf16x4*)(dst + j2 * 64) = u.v;
    }
  };
  auto loadB = [&](int T, int bs) {          // 8 coalesced 1KB wave-loads (L2)
    #pragma unroll
    for (int ct = 0; ct < 8; ct++) {
      union bfu u;
      u.v = *(const bf16x8*)(bpb + (long)T * 16384 + ct * 512);
      bfr[bs][ct] = u.s;
    }
  };
  auto compute = [&](int b, int s, int bs) { // one K-step: 4 ds_read + 32 MFMA
    const __bf16* base = (b ? ar1 : ar0) + s * 2080;
    #pragma unroll
    for (int rt = 0; rt < 4; rt++) {
      union bfu u;
      u.v = *(const bf16x8*)(base + rt * 128);
      #pragma unroll
      for (int ct = 0; ct < 8; ct++)
        acc[rt][ct] = __builtin_amdgcn_mfma_f32_16x16x32_bf16(
            u.s, bfr[bs][ct], acc[rt][ct], 0, 0, 0);
    }
  };

  // prologue: A(P=0) staged into buf0; B(0),B(1) in regs.
  issueA(0);
  loadB(0, 0); loadB(1, 1);
  writeA(0);                   // counted vmcnt wait for ra only; B stays in flight
  BARX();

  // Mega-phase P (reads buf[P&1], writes buf[(P&1)^1]):
  //   issueA(P+1) first (8 HBM loads fly under ~4 steps of compute);
  //   4 K-steps x 32 MFMA with B rolling 1 ahead; cvt+write A(P+1);
  //   ONE barrier per phase.
#define PHASE(P)                                           \
  {                                                        \
    if ((P) < 7) issueA((P) + 1);                          \
    compute((P) & 1, 0, 0);                                \
    loadB((P) * 4 + 2, 0);                                 \
    compute((P) & 1, 1, 1);                                \
    loadB((P) * 4 + 3, 1);                                 \
    compute((P) & 1, 2, 0);                                \
    if ((P) < 7) loadB((P) * 4 + 4, 0);                    \
    compute((P) & 1, 3, 1);                                \
    if ((P) < 7) loadB((P) * 4 + 5, 1);                    \
    if ((P) < 7) { writeA(((P) & 1) ^ 1); BARX(); }        \
  }

  PHASE(0) PHASE(1) PHASE(2) PHASE(3)
  PHASE(4) PHASE(5) PHASE(6) PHASE(7)
#undef PHASE

  // ---- epilogue: score[row] = sum_n v[n] * tanh(acc + hproj[row][n])
  // rows 0..63: global m = blk*64+row = s*64+b -> s=blk, b=row.
  float vv[8];
  #pragma unroll
  for (int ct = 0; ct < 8; ct++) vv[ct] = v[wc * 128 + ct * 16 + t];

  #pragma unroll
  for (int rt = 0; rt < 4; rt++) {
    #pragma unroll
    for (int r = 0; r < 4; r++) {
      int row = rt * 16 + q * 4 + r;              // C/D: row=(lane>>4)*4+reg
      const float* hrow = hproj + row * 512 + wc * 128 + t;
      float s = 0.f;
      #pragma unroll
      for (int ct = 0; ct < 8; ct++) {
        float e  = acc[rt][ct][r] + hrow[ct * 16];
        float ex = __builtin_amdgcn_exp2f(e * LOG2E_X2);        // e^(2x)
        float th = 1.f - 2.f * __builtin_amdgcn_rcpf(ex + 1.f); // tanh(x)
        s = fmaf(vv[ct], th, s);
      }
      s += __shfl_xor(s, 1);
      s += __shfl_xor(s, 2);
      s += __shfl_xor(s, 4);
      s += __shfl_xor(s, 8);
      if (t == 0) atomicAdd(&bscore[row], s);
    }
  }
  __syncthreads();   // once, end of kernel
  if (tid < 64) scores[(long)tid * 1024 + blockIdx.x] = bscore[tid];
}

// ---- kernel 3: softmax over s for each b
__global__ void softmax_kernel(const float* __restrict__ scores,
                               float* __restrict__ out) {
  const int b_   = blockIdx.x;
  const int tid  = threadIdx.x;
  const int lane = tid & 63;
  const int wv   = tid >> 6;
  __shared__ float redmax[4], redsum[4];

  float x[4];
  #pragma unroll
  for (int i = 0; i < 4; i++) x[i] = scores[b_ * 1024 + i * 256 + tid];
  float mx = fmaxf(fmaxf(x[0], x[1]), fmaxf(x[2], x[3]));
  #pragma unroll
  for (int off = 1; off < 64; off <<= 1) mx = fmaxf(mx, __shfl_xor(mx, off));
  if (lane == 0) redmax[wv] = mx;
  __syncthreads();
  mx = fmaxf(fmaxf(redmax[0], redmax[1]), fmaxf(redmax[2], redmax[3]));

  float e[4], s = 0.f;
  #pragma unroll
  for (int i = 0; i < 4; i++) { e[i] = __expf(x[i] - mx); s += e[i]; }
  #pragma unroll
  for (int off = 1; off < 64; off <<= 1) s += __shfl_xor(s, off);
  if (lane == 0) redsum[wv] = s;
  __syncthreads();
  s = redsum[0] + redsum[1] + redsum[2] + redsum[3];
  float inv = 1.f / s;
  #pragma unroll
  for (int i = 0; i < 4; i++) out[b_ * 1024 + i * 256 + tid] = e[i] * inv;
}

extern "C" void kernel_launch(void* const* d_in, const int* in_sizes, int n_in,
                              void* d_out, int out_size, void* d_ws, size_t ws_size,
                              hipStream_t stream) {
  (void)in_sizes; (void)n_in; (void)out_size; (void)ws_size;
  const float* hidden = (const float*)d_in[0];   // [64,512]
  const float* enc    = (const float*)d_in[1];   // [1024,64,1024]
  const float* W      = (const float*)d_in[2];   // [1536,512]
  const float* bias   = (const float*)d_in[3];   // [512]
  const float* v      = (const float*)d_in[4];   // [512]
  float* out = (float*)d_out;                    // [64,1024]

  char* ws = (char*)d_ws;
  __bf16* Bp    = (__bf16*)ws;                            // 1 MB (packed B)
  float*  hproj = (float*)(ws + (1 << 20));               // 128 KB
  float*  scores= (float*)(ws + (1 << 20) + (128 << 10)); // 256 KB

  hipMemsetAsync(hproj, 0, 64 * 512 * sizeof(float), stream);
  wt_convert<<<128, 256, 0, stream>>>(W, Bp);
  hproj_kernel<<<256, 512, 0, stream>>>(hidden, W, bias, hproj);
  gemm_score<<<1024, 256, 0, stream>>>(enc, Bp, hproj, v, scores);
  softmax_kernel<<<64, 256, 0, stream>>>(scores, out);
}

// Round 12
// 405.916 us; speedup vs baseline: 1.1000x; 1.1000x over previous
//
#include <hip/hip_runtime.h>
#include <stdint.h>

// ---------------------------------------------------------------------------
// scores[b,s] = v . tanh( hidden[b] @ Wh + bias + enc[s,b] @ We )
// out[b,s]   = softmax_s(scores)
// Big GEMM: enc_flat[M=65536,K=1024] @ We[K=1024,N=512], bf16 MFMA.
// R13: R12 proved contiguous-line staging doubles achieved HBM BW
//     (790 -> 1434 GB/s) but spilled ~60 regs (WRITE_SIZE 61MB): the
//     32KB-stride staging loads need 8 addr pairs (+16 VGPR) and with
//     ra(32)+bfr[2][8](64) the arch budget beside 128 AGPRs overflowed.
//     Fix: single rolling bfr[8] (-32 VGPR; R10 proved correctness, L2
//     refill hides under the 32-MFMA step + 2-block TLP). Everything else
//     kept: 8-lines-per-instr A staging, BK=128 mega-phases (128 MFMA per
//     barrier, 8 barriers), packed fragment-order B, XOR-swizzle + pad.
// ---------------------------------------------------------------------------

typedef float  floatx4 __attribute__((ext_vector_type(4)));
typedef __bf16 bf16x4  __attribute__((ext_vector_type(4)));
typedef __bf16 bf16x8  __attribute__((ext_vector_type(8)));
typedef short  short8  __attribute__((ext_vector_type(8)));

union bfu  { bf16x8 v; short8 s; };
union bfu4 { bf16x4 v; uint2 u; };

#define LOG2E_X2 2.8853900817779268f
#define SB() __builtin_amdgcn_sched_barrier(0)

// raw barrier: wait own LDS ops only; global prefetches ride across.
#define BARX()                                             \
  do {                                                     \
    asm volatile("s_waitcnt lgkmcnt(0)" ::: "memory");     \
    SB();                                                  \
    __builtin_amdgcn_s_barrier();                          \
    SB();                                                  \
  } while (0)

// ---- kernel 0: W[512:1536,:] -> fragment-packed bf16 B.
// Bp frag(T,wc,ct) base elem = ((T*4+wc)*8+ct)*512; lane (q*16+t) holds 8 k.
__global__ void wt_convert(const float* __restrict__ W, __bf16* __restrict__ Bp) {
  __shared__ float tile[64][65];                 // +1 pad: conflict-free both ways
  const int kt = blockIdx.x >> 3;                // 16 k-tiles (64 k each)
  const int nt = blockIdx.x & 7;                 // 8 n-tiles (64 n each)
  const int c  = threadIdx.x & 63;
  const int r4 = threadIdx.x >> 6;               // 4 rows per pass
  #pragma unroll 4
  for (int i = 0; i < 16; i++) {
    int r = i * 4 + r4;                          // k-local
    tile[r][c] = W[(long)(512 + kt * 64 + r) * 512 + nt * 64 + c];
  }
  __syncthreads();
  const int n_loc = threadIdx.x & 63;
  const int kc4   = threadIdx.x >> 6;            // 0..3
  const int n_g   = nt * 64 + n_loc;
  const int wc    = n_g >> 7;
  const int ct    = (n_g >> 4) & 7;
  const int t     = n_g & 15;
  #pragma unroll
  for (int i = 0; i < 2; i++) {
    int chunk = i * 4 + kc4;                     // k_loc = chunk*8 + j
    int k_g   = kt * 64 + chunk * 8;
    int T     = k_g >> 5;
    int q     = (k_g >> 3) & 3;
    union bfu u;
    #pragma unroll
    for (int j = 0; j < 8; j++) u.v[j] = (__bf16)tile[chunk * 8 + j][n_loc];
    long cidx = ((long)(T * 4 + wc) * 8 + ct) * 64 + q * 16 + t;
    *(bf16x8*)(Bp + cidx * 8) = u.v;
  }
}

// ---- kernel 1: hproj[b][n] = bias[n] + sum_k hidden[b,k] * W[k,n]  (k<512)
__global__ void hproj_kernel(const float* __restrict__ hidden,
                             const float* __restrict__ W,
                             const float* __restrict__ bias,
                             float* __restrict__ hproj) {
  const int tid = threadIdx.x;            // n
  const int b_  = blockIdx.x >> 2;
  const int kc  = blockIdx.x & 3;
  __shared__ float hid[128];
  if (tid < 128) hid[tid] = hidden[b_ * 512 + kc * 128 + tid];
  __syncthreads();
  float acc = (kc == 0) ? bias[tid] : 0.f;
  const float* Wp = W + (long)(kc * 128) * 512 + tid;
  #pragma unroll 8
  for (int k = 0; k < 128; k++) acc = fmaf(hid[k], Wp[(long)k * 512], acc);
  atomicAdd(&hproj[b_ * 512 + tid], acc);
}

// ---- kernel 2: GEMM + tanh/v-dot epilogue; BK=128 mega-phases,
//                contiguous-line A staging, single rolling B buffer.
// LDS buffer (bf16): element (m, step s, k-in-step kk=c*8+jj):
//   addr = s*2080 + c*512 + ((m*8) ^ (c*16)) + jj        (2080 = 2048+32 pad)
// Staging (thread tid, chunk j2 = 0..7):
//   row m = j2*8 + (tid>>5); 4 floats at k-chunk (tid&31)*4.
//   Global: instr j2 = 2 rows x 512B contiguous = 8 lines.
//   LDS: s=(tid&31)>>3, c=((tid&31)>>1)&3, j0=(tid&1)*4 ->
//     awoff = s*2080 + c*512 + (((tid>>5)*8) ^ (c*16)) + j0; + j2*64.
__global__ __launch_bounds__(256, 2) void gemm_score(
    const float* __restrict__ enc,    // [65536][1024] fp32
    const __bf16* __restrict__ Bp,    // packed B, 1 MB
    const float* __restrict__ hproj,  // [64][512]
    const float* __restrict__ v,      // [512]
    float* __restrict__ scores)       // [64][1024]  ([b][s])
{
  __shared__ __bf16 ldsA[2][8320];   // 2 x 16.25 KB
  __shared__ float bscore[64];

  const int tid  = threadIdx.x;
  const int lane = tid & 63;
  const int wc   = tid >> 6;      // wave -> n-range [wc*128, +128)
  const int q    = lane >> 4;
  const int t    = lane & 15;
  const long m0  = (long)blockIdx.x * 64;

  // staging: base row = tid>>5 (chunk j2 adds j2*8 rows); col = (tid&31)*4
  const float* ap = enc + (m0 + (tid >> 5)) * 1024 + (tid & 31) * 4;
  const int skk = tid & 31;
  const int ss  = skk >> 3;
  const int cc  = (skk >> 1) & 3;
  const int j0  = (skk & 1) * 4;
  const int awoff = ss * 2080 + cc * 512 + (((tid >> 5) * 8) ^ (cc * 16)) + j0;

  // fragment read bases (step/rt offsets are compile-time immediates)
  const __bf16* ar0 = &ldsA[0][q * 512 + ((t * 8) ^ (q * 16))];
  const __bf16* ar1 = &ldsA[1][q * 512 + ((t * 8) ^ (q * 16))];

  // packed-B per-lane base
  const __bf16* bpb = Bp + (long)wc * 4096 + (long)lane * 8;

  if (tid < 64) bscore[tid] = 0.f;

  floatx4 acc[4][8];
  #pragma unroll
  for (int i = 0; i < 4; i++)
    #pragma unroll
    for (int j = 0; j < 8; j++)
      acc[i][j] = (floatx4){0.f, 0.f, 0.f, 0.f};

  floatx4 ra[8];       // A staging: 8 x 16B chunks (8 rows), 32 VGPR
  short8  bfr[8];      // B fragments, single rolling buffer (32 VGPR)

  auto issueA = [&](int P) {                 // 8 contiguous-line 16B loads
    const float* p = ap + P * 128;
    #pragma unroll
    for (int j2 = 0; j2 < 8; j2++)
      ra[j2] = *(const floatx4*)(p + (long)j2 * 8 * 1024);
  };
  auto writeA = [&](int b) {                 // cvt once + 8 x ds_write_b64
    __bf16* dst = &ldsA[b][awoff];
    #pragma unroll
    for (int j2 = 0; j2 < 8; j2++) {
      union bfu4 u;
      #pragma unroll
      for (int j = 0; j < 4; j++) u.v[j] = (__bf16)ra[j2][j];
      *(bf16x4*)(dst + j2 * 64) = u.v;
    }
  };
  auto loadB = [&](int T) {                  // 8 coalesced 1KB wave-loads (L2)
    #pragma unroll
    for (int ct = 0; ct < 8; ct++) {
      union bfu u;
      u.v = *(const bf16x8*)(bpb + (long)T * 16384 + ct * 512);
      bfr[ct] = u.s;
    }
  };
  auto compute = [&](int b, int s) {         // one K-step: 4 ds_read + 32 MFMA
    const __bf16* base = (b ? ar1 : ar0) + s * 2080;
    #pragma unroll
    for (int rt = 0; rt < 4; rt++) {
      union bfu u;
      u.v = *(const bf16x8*)(base + rt * 128);
      #pragma unroll
      for (int ct = 0; ct < 8; ct++)
        acc[rt][ct] = __builtin_amdgcn_mfma_f32_16x16x32_bf16(
            u.s, bfr[ct], acc[rt][ct], 0, 0, 0);
    }
  };

  // prologue: A(P=0) staged into buf0; B(T=0) in regs.
  issueA(0);
  loadB(0);
  writeA(0);            // counted vmcnt wait for ra only; B stays in flight
  BARX();

  // Mega-phase P (reads buf[P&1], writes buf[(P&1)^1]):
  //   issueA(P+1) first (8 HBM loads fly under 4 K-steps of compute);
  //   4 K-steps x 32 MFMA, B reloaded right after each consumption
  //   (~160cy MFMA + TLP covers the ~200cy L2 refill);
  //   cvt+write A(P+1); ONE barrier per phase.
#define PHASE(P)                                           \
  {                                                        \
    if ((P) < 7) issueA((P) + 1);                          \
    compute((P) & 1, 0);                                   \
    loadB((P) * 4 + 1);                                    \
    compute((P) & 1, 1);                                   \
    loadB((P) * 4 + 2);                                    \
    compute((P) & 1, 2);                                   \
    loadB((P) * 4 + 3);                                    \
    compute((P) & 1, 3);                                   \
    if ((P) < 7) {                                         \
      loadB((P) * 4 + 4);                                  \
      writeA(((P) & 1) ^ 1);                               \
      BARX();                                              \
    }                                                      \
  }

  PHASE(0) PHASE(1) PHASE(2) PHASE(3)
  PHASE(4) PHASE(5) PHASE(6) PHASE(7)
#undef PHASE

  // ---- epilogue: score[row] = sum_n v[n] * tanh(acc + hproj[row][n])
  // rows 0..63: global m = blk*64+row = s*64+b -> s=blk, b=row.
  float vv[8];
  #pragma unroll
  for (int ct = 0; ct < 8; ct++) vv[ct] = v[wc * 128 + ct * 16 + t];

  #pragma unroll
  for (int rt = 0; rt < 4; rt++) {
    #pragma unroll
    for (int r = 0; r < 4; r++) {
      int row = rt * 16 + q * 4 + r;              // C/D: row=(lane>>4)*4+reg
      const float* hrow = hproj + row * 512 + wc * 128 + t;
      float s = 0.f;
      #pragma unroll
      for (int ct = 0; ct < 8; ct++) {
        float e  = acc[rt][ct][r] + hrow[ct * 16];
        float ex = __builtin_amdgcn_exp2f(e * LOG2E_X2);        // e^(2x)
        float th = 1.f - 2.f * __builtin_amdgcn_rcpf(ex + 1.f); // tanh(x)
        s = fmaf(vv[ct], th, s);
      }
      s += __shfl_xor(s, 1);
      s += __shfl_xor(s, 2);
      s += __shfl_xor(s, 4);
      s += __shfl_xor(s, 8);
      if (t == 0) atomicAdd(&bscore[row], s);
    }
  }
  __syncthreads();   // once, end of kernel
  if (tid < 64) scores[(long)tid * 1024 + blockIdx.x] = bscore[tid];
}

// ---- kernel 3: softmax over s for each b
__global__ void softmax_kernel(const float* __restrict__ scores,
                               float* __restrict__ out) {
  const int b_   = blockIdx.x;
  const int tid  = threadIdx.x;
  const int lane = tid & 63;
  const int wv   = tid >> 6;
  __shared__ float redmax[4], redsum[4];

  float x[4];
  #pragma unroll
  for (int i = 0; i < 4; i++) x[i] = scores[b_ * 1024 + i * 256 + tid];
  float mx = fmaxf(fmaxf(x[0], x[1]), fmaxf(x[2], x[3]));
  #pragma unroll
  for (int off = 1; off < 64; off <<= 1) mx = fmaxf(mx, __shfl_xor(mx, off));
  if (lane == 0) redmax[wv] = mx;
  __syncthreads();
  mx = fmaxf(fmaxf(redmax[0], redmax[1]), fmaxf(redmax[2], redmax[3]));

  float e[4], s = 0.f;
  #pragma unroll
  for (int i = 0; i < 4; i++) { e[i] = __expf(x[i] - mx); s += e[i]; }
  #pragma unroll
  for (int off = 1; off < 64; off <<= 1) s += __shfl_xor(s, off);
  if (lane == 0) redsum[wv] = s;
  __syncthreads();
  s = redsum[0] + redsum[1] + redsum[2] + redsum[3];
  float inv = 1.f / s;
  #pragma unroll
  for (int i = 0; i < 4; i++) out[b_ * 1024 + i * 256 + tid] = e[i] * inv;
}

extern "C" void kernel_launch(void* const* d_in, const int* in_sizes, int n_in,
                              void* d_out, int out_size, void* d_ws, size_t ws_size,
                              hipStream_t stream) {
  (void)in_sizes; (void)n_in; (void)out_size; (void)ws_size;
  const float* hidden = (const float*)d_in[0];   // [64,512]
  const float* enc    = (const float*)d_in[1];   // [1024,64,1024]
  const float* W      = (const float*)d_in[2];   // [1536,512]
  const float* bias   = (const float*)d_in[3];   // [512]
  const float* v      = (const float*)d_in[4];   // [512]
  float* out = (float*)d_out;                    // [64,1024]

  char* ws = (char*)d_ws;
  __bf16* Bp    = (__bf16*)ws;                            // 1 MB (packed B)
  float*  hproj = (float*)(ws + (1 << 20));               // 128 KB
  float*  scores= (float*)(ws + (1 << 20) + (128 << 10)); // 256 KB

  hipMemsetAsync(hproj, 0, 64 * 512 * sizeof(float), stream);
  wt_convert<<<128, 256, 0, stream>>>(W, Bp);
  hproj_kernel<<<256, 512, 0, stream>>>(hidden, W, bias, hproj);
  gemm_score<<<1024, 256, 0, stream>>>(enc, Bp, hproj, v, scores);
  softmax_kernel<<<64, 256, 0, stream>>>(scores, out);
}